// Round 10
// baseline (505.699 us; speedup 1.0000x reference)
//
#include <hip/hip_runtime.h>

#define N_NODES 50000
#define N_EDGES 800000
#define CH 256
#define NUM_GRAPHS 512
#define LEAKY 0.01f
#define LN_EPS 1e-5f
#define NBLK ((N_NODES + 255) / 256)   // 196

typedef __attribute__((ext_vector_type(4))) float f32x4;
typedef __attribute__((ext_vector_type(2))) float f32x2;
typedef __attribute__((ext_vector_type(8))) short bf16x8;

__device__ __forceinline__ float b2f(unsigned short u) {
    union { unsigned int i; float f; } x; x.i = ((unsigned int)u) << 16; return x.f;
}
__device__ __forceinline__ unsigned short f2b(float f) {  // round-to-nearest-even
    union { float f; unsigned int i; } x; x.f = f;
    unsigned int r = x.i + 0x7fffu + ((x.i >> 16) & 1u);
    return (unsigned short)(r >> 16);
}
__device__ __forceinline__ f32x2 b2f2(unsigned int u) {
    union { unsigned int i; float f; } lo, hi;
    lo.i = u << 16; hi.i = u & 0xffff0000u;
    f32x2 r; r.x = lo.f; r.y = hi.f; return r;
}
__device__ __forceinline__ unsigned int pack2(float a, float b) {
    return (unsigned int)f2b(a) | ((unsigned int)f2b(b) << 16);
}
// async global->LDS, 16B per lane; LDS dest is wave-uniform base + lane*16
__device__ __forceinline__ void gload16(const void* g, void* l) {
    __builtin_amdgcn_global_load_lds((const __attribute__((address_space(1))) unsigned int*)g,
                                     (__attribute__((address_space(3))) unsigned int*)l, 16, 0, 0);
}

__global__ void zero_ints(int* __restrict__ p, int n) {
    int i = blockIdx.x * blockDim.x + threadIdx.x;
    if (i < n) p[i] = 0;
}

__global__ void count_deg(const int* __restrict__ dst, int* __restrict__ cnt) {
    int e = blockIdx.x * blockDim.x + threadIdx.x;
    if (e < N_EDGES) atomicAdd(&cnt[dst[e]], 1);
}

__global__ __launch_bounds__(256) void block_reduce(const int* __restrict__ cnt,
                                                    int* __restrict__ bsum,
                                                    float* __restrict__ dinv) {
    __shared__ int s[256];
    int tid = threadIdx.x;
    int i = blockIdx.x * 256 + tid;
    int v = (i < N_NODES) ? cnt[i] : 0;
    if (i < N_NODES) dinv[i] = rsqrtf(1.0f + (float)v);
    s[tid] = v;
    __syncthreads();
    #pragma unroll
    for (int off = 128; off > 0; off >>= 1) {
        if (tid < off) s[tid] += s[tid + off];
        __syncthreads();
    }
    if (tid == 0) bsum[blockIdx.x] = s[0];
}

__global__ __launch_bounds__(256) void scan_bsums(int* __restrict__ bsum) {
    __shared__ int s[256];
    int tid = threadIdx.x;
    int v = (tid < NBLK) ? bsum[tid] : 0;
    s[tid] = v;
    __syncthreads();
    #pragma unroll
    for (int off = 1; off < 256; off <<= 1) {
        int t = (tid >= off) ? s[tid - off] : 0;
        __syncthreads();
        s[tid] += t;
        __syncthreads();
    }
    if (tid < NBLK) bsum[tid] = s[tid] - v;
}

__global__ __launch_bounds__(256) void block_scan(const int* __restrict__ cnt,
                                                  const int* __restrict__ bsum,
                                                  int* __restrict__ rowptr,
                                                  int* __restrict__ cursor) {
    __shared__ int s[256];
    int tid = threadIdx.x;
    int i = blockIdx.x * 256 + tid;
    int v = (i < N_NODES) ? cnt[i] : 0;
    s[tid] = v;
    __syncthreads();
    #pragma unroll
    for (int off = 1; off < 256; off <<= 1) {
        int t = (tid >= off) ? s[tid - off] : 0;
        __syncthreads();
        s[tid] += t;
        __syncthreads();
    }
    if (i < N_NODES) {
        int val = bsum[blockIdx.x] + s[tid] - v;   // exclusive: start of row i
        rowptr[i] = val;
        cursor[i] = val;
        if (i == N_NODES - 1) rowptr[N_NODES] = bsum[blockIdx.x] + s[tid];
    }
}

__global__ void fill_csr(const int* __restrict__ src, const int* __restrict__ dst,
                         int* __restrict__ cursor, int* __restrict__ col) {
    int e = blockIdx.x * blockDim.x + threadIdx.x;
    if (e < N_EDGES) {
        int d = dst[e];
        int p = atomicAdd(&cursor[d], 1);
        col[p] = src[e];
    }
}

// both W1 and W2 in one launch
__global__ void transpose_w2(const float* __restrict__ W1f, const float* __restrict__ W2f,
                             unsigned short* __restrict__ WT1, unsigned short* __restrict__ WT2) {
    int k = blockIdx.x & 255;
    const float* W = (blockIdx.x >> 8) ? W2f : W1f;
    unsigned short* WT = (blockIdx.x >> 8) ? WT2 : WT1;
    int n = threadIdx.x;
    WT[n * CH + k] = f2b(W[k * CH + n]);
}

// ---------------- MFMA GEMMs
#define BM 128
#define BN 128
#define BK 64
#define SWZ(row, kb) (((row) * 128 + (kb) * 16) ^ (((row) & 7) << 4))

// layer 1: A f32 (harness x, guarded reg staging + cvt); B via global_load_lds
__global__ __launch_bounds__(256) void gemm_f32a(const float* __restrict__ Af,
                                                 const unsigned short* __restrict__ BT,
                                                 const float* __restrict__ dinv,
                                                 unsigned short* __restrict__ out) {
    __shared__ unsigned short As[BM * BK];
    __shared__ unsigned short Bs[BN * BK];
    const int row0 = blockIdx.x * BM;
    const int col0 = blockIdx.y * BN;
    const int tid = threadIdx.x;
    const int w = tid >> 6, l = tid & 63;
    const int wr = w >> 1, wc = w & 1;
    const int lr = l & 15, lg = l >> 4;
    const int sr = l >> 3, kbp = l & 7;

    f32x4 acc[4][4] = {};

    for (int k0 = 0; k0 < CH; k0 += BK) {
        #pragma unroll
        for (int it = 0; it < 4; it++) {
            const int R = (w * 4 + it) * 8;
            const int r = R + sr;
            const int kb = kbp ^ (r & 7);
            gload16(&BT[(size_t)(col0 + r) * CH + k0 + kb * 8], (char*)Bs + R * 128);
        }
        #pragma unroll
        for (int it = 0; it < 4; it++) {
            int cidx = it * 256 + tid;
            int r = cidx >> 3, kb = cidx & 7;
            int grow = row0 + r;
            uint4 ua = make_uint4(0u, 0u, 0u, 0u);
            if (grow < N_NODES) {
                const float* ap = &Af[(size_t)grow * CH + k0 + kb * 8];
                float4 v0 = *(const float4*)ap;
                float4 v1 = *(const float4*)(ap + 4);
                ua = make_uint4(pack2(v0.x, v0.y), pack2(v0.z, v0.w),
                                pack2(v1.x, v1.y), pack2(v1.z, v1.w));
            }
            *(uint4*)((char*)As + SWZ(r, kb)) = ua;
        }
        __syncthreads();
        #pragma unroll
        for (int ks = 0; ks < 2; ks++) {
            bf16x8 af[4], bfr[4];
            #pragma unroll
            for (int fm = 0; fm < 4; fm++) {
                int r = wr * 64 + fm * 16 + lr;
                af[fm] = *(const bf16x8*)((const char*)As + SWZ(r, ks * 4 + lg));
            }
            #pragma unroll
            for (int fn = 0; fn < 4; fn++) {
                int r = wc * 64 + fn * 16 + lr;
                bfr[fn] = *(const bf16x8*)((const char*)Bs + SWZ(r, ks * 4 + lg));
            }
            #pragma unroll
            for (int fm = 0; fm < 4; fm++)
                #pragma unroll
                for (int fn = 0; fn < 4; fn++)
                    acc[fm][fn] = __builtin_amdgcn_mfma_f32_16x16x32_bf16(af[fm], bfr[fn], acc[fm][fn], 0, 0, 0);
        }
        __syncthreads();
    }
    #pragma unroll
    for (int fm = 0; fm < 4; fm++) {
        #pragma unroll
        for (int r = 0; r < 4; r++) {
            int grow = row0 + wr * 64 + fm * 16 + lg * 4 + r;
            if (grow < N_NODES) {
                float s = dinv[grow];
                #pragma unroll
                for (int fn = 0; fn < 4; fn++) {
                    int gcol = col0 + wc * 64 + fn * 16 + lr;
                    out[(size_t)grow * CH + gcol] = f2b(acc[fm][fn][r] * s);
                }
            }
        }
    }
}

// layer 2: A = LN+leaky of raw1 (fused during staging, musig precomputed); B via gload_lds
__global__ __launch_bounds__(256) void gemm_ln_a(const unsigned short* __restrict__ raw,
                                                 const float2* __restrict__ musig,
                                                 const float* __restrict__ lnw,
                                                 const float* __restrict__ lnb,
                                                 const unsigned short* __restrict__ BT,
                                                 const float* __restrict__ dinv,
                                                 unsigned short* __restrict__ out) {
    __shared__ unsigned short As[BM * BK];
    __shared__ unsigned short Bs[BN * BK];
    const int row0 = blockIdx.x * BM;
    const int col0 = blockIdx.y * BN;
    const int tid = threadIdx.x;
    const int w = tid >> 6, l = tid & 63;
    const int wr = w >> 1, wc = w & 1;
    const int lr = l & 15, lg = l >> 4;
    const int sr = l >> 3, kbp = l & 7;

    f32x4 acc[4][4] = {};

    for (int k0 = 0; k0 < CH; k0 += BK) {
        #pragma unroll
        for (int it = 0; it < 4; it++) {
            const int R = (w * 4 + it) * 8;
            const int r = R + sr;
            const int kb = kbp ^ (r & 7);
            gload16(&BT[(size_t)(col0 + r) * CH + k0 + kb * 8], (char*)Bs + R * 128);
        }
        #pragma unroll
        for (int it = 0; it < 4; it++) {
            int cidx = it * 256 + tid;
            int r = cidx >> 3, kb = cidx & 7;
            int grow = row0 + r;
            uint4 ua = make_uint4(0u, 0u, 0u, 0u);
            if (grow < N_NODES) {
                uint4 u = ((const uint4*)raw)[(size_t)grow * 32 + (k0 >> 3) + kb];
                float2 ms = musig[grow];                 // {mu, rstd}
                float4 w0 = ((const float4*)lnw)[(k0 >> 2) + kb * 2];
                float4 w1 = ((const float4*)lnw)[(k0 >> 2) + kb * 2 + 1];
                float4 b0 = ((const float4*)lnb)[(k0 >> 2) + kb * 2];
                float4 b1 = ((const float4*)lnb)[(k0 >> 2) + kb * 2 + 1];
                f32x2 v0 = b2f2(u.x), v1 = b2f2(u.y), v2 = b2f2(u.z), v3 = b2f2(u.w);
                float y0 = (v0.x - ms.x) * ms.y * w0.x + b0.x;
                float y1 = (v0.y - ms.x) * ms.y * w0.y + b0.y;
                float y2 = (v1.x - ms.x) * ms.y * w0.z + b0.z;
                float y3 = (v1.y - ms.x) * ms.y * w0.w + b0.w;
                float y4 = (v2.x - ms.x) * ms.y * w1.x + b1.x;
                float y5 = (v2.y - ms.x) * ms.y * w1.y + b1.y;
                float y6 = (v3.x - ms.x) * ms.y * w1.z + b1.z;
                float y7 = (v3.y - ms.x) * ms.y * w1.w + b1.w;
                y0 = fmaxf(y0, LEAKY * y0); y1 = fmaxf(y1, LEAKY * y1);
                y2 = fmaxf(y2, LEAKY * y2); y3 = fmaxf(y3, LEAKY * y3);
                y4 = fmaxf(y4, LEAKY * y4); y5 = fmaxf(y5, LEAKY * y5);
                y6 = fmaxf(y6, LEAKY * y6); y7 = fmaxf(y7, LEAKY * y7);
                ua = make_uint4(pack2(y0, y1), pack2(y2, y3), pack2(y4, y5), pack2(y6, y7));
            }
            *(uint4*)((char*)As + SWZ(r, kb)) = ua;
        }
        __syncthreads();
        #pragma unroll
        for (int ks = 0; ks < 2; ks++) {
            bf16x8 af[4], bfr[4];
            #pragma unroll
            for (int fm = 0; fm < 4; fm++) {
                int r = wr * 64 + fm * 16 + lr;
                af[fm] = *(const bf16x8*)((const char*)As + SWZ(r, ks * 4 + lg));
            }
            #pragma unroll
            for (int fn = 0; fn < 4; fn++) {
                int r = wc * 64 + fn * 16 + lr;
                bfr[fn] = *(const bf16x8*)((const char*)Bs + SWZ(r, ks * 4 + lg));
            }
            #pragma unroll
            for (int fm = 0; fm < 4; fm++)
                #pragma unroll
                for (int fn = 0; fn < 4; fn++)
                    acc[fm][fn] = __builtin_amdgcn_mfma_f32_16x16x32_bf16(af[fm], bfr[fn], acc[fm][fn], 0, 0, 0);
        }
        __syncthreads();
    }
    #pragma unroll
    for (int fm = 0; fm < 4; fm++) {
        #pragma unroll
        for (int r = 0; r < 4; r++) {
            int grow = row0 + wr * 64 + fm * 16 + lg * 4 + r;
            if (grow < N_NODES) {
                float s = dinv[grow];
                #pragma unroll
                for (int fn = 0; fn < 4; fn++) {
                    int gcol = col0 + wc * 64 + fn * 16 + lr;
                    out[(size_t)grow * CH + gcol] = f2b(acc[fm][fn][r] * s);
                }
            }
        }
    }
}

// ---------------- gather, 32-CHANNEL SLICE per block (fits 3.2MB/XCD in 4MB L2)
// b&7 = slice (XCD round-robin); wave processes 8 edges/iter: lane=(es=lane>>3, c=lane&7),
// each lane loads 8B (4 ch). After loop: reduce over es, LN partials to stats[d*16+slice*2].
__global__ __launch_bounds__(256) void gather_slice(const unsigned short* __restrict__ h,
                                                    const int* __restrict__ rowptr,
                                                    const int* __restrict__ col,
                                                    const float* __restrict__ dinv,
                                                    const float* __restrict__ bias,
                                                    unsigned short* __restrict__ raw,
                                                    float* __restrict__ stats) {
    const int w = threadIdx.x >> 6, lane = threadIdx.x & 63;
    const unsigned b = blockIdx.x;
    const int slice = b & 7;
    const int d = (int)(b >> 3) * 4 + w;      // [0,50000)
    const int c = lane & 7, es = lane >> 3;
    const int du2 = slice * 8 + c;            // uint2 index within 64-uint2 row
    const uint2* __restrict__ h2 = (const uint2*)h;

    f32x2 acc01 = {0.f, 0.f}, acc23 = {0.f, 0.f};
    if (es == 0) {                             // self loop, added once
        uint2 u = h2[(size_t)d * 64 + du2];
        acc01 = b2f2(u.x); acc23 = b2f2(u.y);
    }

    const int e0 = rowptr[d], e1 = rowptr[d + 1];
    for (int base = e0; base < e1; base += 64) {
        int n = e1 - base; if (n > 64) n = 64;
        int cidx = (lane < n) ? col[base + lane] : 0;
        const int full = n >> 3;
        for (int j = 0; j < full; j++) {
            int s = __shfl(cidx, j * 8 + es);
            uint2 u = h2[(size_t)s * 64 + du2];
            acc01 += b2f2(u.x); acc23 += b2f2(u.y);
        }
        const int rem = n & 7;
        if (rem) {
            int s = __shfl(cidx, full * 8 + (es < rem ? es : 0));
            if (es < rem) {
                uint2 u = h2[(size_t)s * 64 + du2];
                acc01 += b2f2(u.x); acc23 += b2f2(u.y);
            }
        }
    }
    // reduce across the 8 edge-slots (lanes c, c+8, ..., c+56)
    #pragma unroll
    for (int off = 8; off < 64; off <<= 1) {
        acc01.x += __shfl_xor(acc01.x, off); acc01.y += __shfl_xor(acc01.y, off);
        acc23.x += __shfl_xor(acc23.x, off); acc23.y += __shfl_xor(acc23.y, off);
    }
    const float di = dinv[d];
    float4 bb = ((const float4*)bias)[slice * 8 + c];
    float a0 = acc01.x * di + bb.x, a1 = acc01.y * di + bb.y;
    float a2 = acc23.x * di + bb.z, a3 = acc23.y * di + bb.w;
    float s1 = a0 + a1 + a2 + a3;
    float s2 = a0 * a0 + a1 * a1 + a2 * a2 + a3 * a3;
    #pragma unroll
    for (int off = 1; off < 8; off <<= 1) {
        s1 += __shfl_xor(s1, off); s2 += __shfl_xor(s2, off);
    }
    if (lane == 0) {
        stats[d * 16 + slice * 2]     = s1;
        stats[d * 16 + slice * 2 + 1] = s2;
    }
    if (es == 0)
        ((uint2*)raw)[(size_t)d * 64 + du2] = make_uint2(pack2(a0, a1), pack2(a2, a3));
}

// fold 8 per-slice (s1,s2) partials -> {mu, rstd} per node
__global__ void finalize_stats(const float* __restrict__ stats, float2* __restrict__ musig) {
    int d = blockIdx.x * 256 + threadIdx.x;
    if (d < N_NODES) {
        float s1 = 0.f, s2 = 0.f;
        #pragma unroll
        for (int i = 0; i < 8; i++) { s1 += stats[d * 16 + i * 2]; s2 += stats[d * 16 + i * 2 + 1]; }
        float mu = s1 * (1.0f / CH);
        float var = s2 * (1.0f / CH) - mu * mu;
        musig[d] = make_float2(mu, rsqrtf(var + LN_EPS));
    }
}

// pool with fused LN+leaky (musig precomputed)
__global__ __launch_bounds__(256) void pool_ln(const unsigned short* __restrict__ raw,
                                               const float2* __restrict__ musig,
                                               const float* __restrict__ lnw,
                                               const float* __restrict__ lnb,
                                               const int* __restrict__ batch,
                                               float* __restrict__ out) {
    const int g = blockIdx.x;
    const int w = threadIdx.x >> 6, lane = threadIdx.x & 63;
    const int c4 = lane * 4;
    int lo = 0, hi = N_NODES;
    while (lo < hi) { int mid = (lo + hi) >> 1; if (batch[mid] < g) lo = mid + 1; else hi = mid; }
    const int start = lo;
    hi = N_NODES;
    while (lo < hi) { int mid = (lo + hi) >> 1; if (batch[mid] < g + 1) lo = mid + 1; else hi = mid; }
    const int end = lo;

    float4 wv = *(const float4*)&lnw[c4];
    float4 bv = *(const float4*)&lnb[c4];
    float a0 = 0.f, a1 = 0.f, a2 = 0.f, a3 = 0.f;
    for (int n = start + w; n < end; n += 4) {
        uint2 u = ((const uint2*)raw)[(size_t)n * 64 + lane];
        f32x2 r01 = b2f2(u.x), r23 = b2f2(u.y);
        float2 ms = musig[n];
        float y0 = (r01.x - ms.x) * ms.y * wv.x + bv.x;
        float y1 = (r01.y - ms.x) * ms.y * wv.y + bv.y;
        float y2 = (r23.x - ms.x) * ms.y * wv.z + bv.z;
        float y3 = (r23.y - ms.x) * ms.y * wv.w + bv.w;
        a0 += fmaxf(y0, LEAKY * y0);
        a1 += fmaxf(y1, LEAKY * y1);
        a2 += fmaxf(y2, LEAKY * y2);
        a3 += fmaxf(y3, LEAKY * y3);
    }
    __shared__ float4 red[4][64];
    red[w][lane] = make_float4(a0, a1, a2, a3);
    __syncthreads();
    if (w == 0) {
        float4 t0 = red[0][lane], t1 = red[1][lane], t2 = red[2][lane], t3 = red[3][lane];
        const float inv = (end > start) ? 1.0f / (float)(end - start) : 0.0f;
        float4 o = make_float4((t0.x + t1.x + t2.x + t3.x) * inv,
                               (t0.y + t1.y + t2.y + t3.y) * inv,
                               (t0.z + t1.z + t2.z + t3.z) * inv,
                               (t0.w + t1.w + t2.w + t3.w) * inv);
        *(float4*)&out[(size_t)g * CH + lane * 4] = o;
    }
}

static inline size_t align256(size_t x) { return (x + 255) & ~(size_t)255; }

extern "C" void kernel_launch(void* const* d_in, const int* in_sizes, int n_in,
                              void* d_out, int out_size, void* d_ws, size_t ws_size,
                              hipStream_t stream) {
    const float* x    = (const float*)d_in[0];
    const int*   edge = (const int*)d_in[1];
    const int*   batch= (const int*)d_in[2];
    const float* W1   = (const float*)d_in[3];
    const float* b1   = (const float*)d_in[4];
    const float* ln1w = (const float*)d_in[5];
    const float* ln1b = (const float*)d_in[6];
    const float* W2   = (const float*)d_in[7];
    const float* b2   = (const float*)d_in[8];
    const float* ln2w = (const float*)d_in[9];
    const float* ln2b = (const float*)d_in[10];

    const int* src = edge;
    const int* dst = edge + N_EDGES;

    char* p = (char*)d_ws;
    int* cnt    = (int*)p;  p += align256(N_NODES * 4);
    int* cursor = (int*)p;  p += align256(N_NODES * 4);
    int* rowptr = (int*)p;  p += align256((N_NODES + 1) * 4);
    int* bsum   = (int*)p;  p += align256(NBLK * 4);
    float* dinv = (float*)p; p += align256(N_NODES * 4);
    float* stats= (float*)p; p += align256((size_t)N_NODES * 16 * 4);
    float2* musig=(float2*)p; p += align256((size_t)N_NODES * 8);
    int* col    = (int*)p;  p += align256(N_EDGES * 4);
    unsigned short* wt1 = (unsigned short*)p; p += align256(CH * CH * 2);
    unsigned short* wt2 = (unsigned short*)p; p += align256(CH * CH * 2);
    unsigned short* bufH = (unsigned short*)p; p += align256((size_t)N_NODES * CH * 2);  // h1, then h2
    unsigned short* bufR = (unsigned short*)p; p += align256((size_t)N_NODES * CH * 2);  // raw1, then raw2
    p += 32768;  // safety pad

    zero_ints<<<(N_NODES + 255) / 256, 256, 0, stream>>>(cnt, N_NODES);
    count_deg<<<(N_EDGES + 255) / 256, 256, 0, stream>>>(dst, cnt);
    block_reduce<<<NBLK, 256, 0, stream>>>(cnt, bsum, dinv);
    scan_bsums<<<1, 256, 0, stream>>>(bsum);
    block_scan<<<NBLK, 256, 0, stream>>>(cnt, bsum, rowptr, cursor);
    fill_csr<<<(N_EDGES + 255) / 256, 256, 0, stream>>>(src, dst, cursor, col);
    transpose_w2<<<2 * CH, 256, 0, stream>>>(W1, W2, wt1, wt2);

    dim3 ggrid((N_NODES + BM - 1) / BM, CH / BN);
    const int sblocks = (N_NODES / 4) * 8;    // 100000 (node-group x slice), slice = b&7

    gemm_f32a<<<ggrid, 256, 0, stream>>>(x, wt1, dinv, bufH);                       // h1
    gather_slice<<<sblocks, 256, 0, stream>>>(bufH, rowptr, col, dinv, b1, bufR, stats);
    finalize_stats<<<(N_NODES + 255) / 256, 256, 0, stream>>>(stats, musig);
    gemm_ln_a<<<ggrid, 256, 0, stream>>>(bufR, musig, ln1w, ln1b, wt2, dinv, bufH); // h2
    gather_slice<<<sblocks, 256, 0, stream>>>(bufH, rowptr, col, dinv, b2, bufR, stats);
    finalize_stats<<<(N_NODES + 255) / 256, 256, 0, stream>>>(stats, musig);
    pool_ln<<<NUM_GRAPHS, 256, 0, stream>>>(bufR, musig, ln2w, ln2b, batch, (float*)d_out);
}

// Round 11
// 292.435 us; speedup vs baseline: 1.7293x; 1.7293x over previous
//
#include <hip/hip_runtime.h>

#define N_NODES 50000
#define N_EDGES 800000
#define CH 256
#define NUM_GRAPHS 512
#define LEAKY 0.01f
#define LN_EPS 1e-5f
#define NBLK ((N_NODES + 255) / 256)   // 196

typedef __attribute__((ext_vector_type(4))) float f32x4;
typedef __attribute__((ext_vector_type(2))) float f32x2;
typedef __attribute__((ext_vector_type(8))) short bf16x8;

__device__ __forceinline__ float b2f(unsigned short u) {
    union { unsigned int i; float f; } x; x.i = ((unsigned int)u) << 16; return x.f;
}
__device__ __forceinline__ unsigned short f2b(float f) {  // round-to-nearest-even
    union { float f; unsigned int i; } x; x.f = f;
    unsigned int r = x.i + 0x7fffu + ((x.i >> 16) & 1u);
    return (unsigned short)(r >> 16);
}
__device__ __forceinline__ f32x2 b2f2(unsigned int u) {
    union { unsigned int i; float f; } lo, hi;
    lo.i = u << 16; hi.i = u & 0xffff0000u;
    f32x2 r; r.x = lo.f; r.y = hi.f; return r;
}
__device__ __forceinline__ unsigned int pack2(float a, float b) {
    return (unsigned int)f2b(a) | ((unsigned int)f2b(b) << 16);
}
// async global->LDS, 16B per lane; LDS dest is wave-uniform base + lane*16
__device__ __forceinline__ void gload16(const void* g, void* l) {
    __builtin_amdgcn_global_load_lds((const __attribute__((address_space(1))) unsigned int*)g,
                                     (__attribute__((address_space(3))) unsigned int*)l, 16, 0, 0);
}

__global__ void zero_ints(int* __restrict__ p, int n) {
    int i = blockIdx.x * blockDim.x + threadIdx.x;
    if (i < n) p[i] = 0;
}

__global__ void count_deg(const int* __restrict__ dst, int* __restrict__ cnt) {
    int e = blockIdx.x * blockDim.x + threadIdx.x;
    if (e < N_EDGES) atomicAdd(&cnt[dst[e]], 1);
}

__global__ __launch_bounds__(256) void block_reduce(const int* __restrict__ cnt,
                                                    int* __restrict__ bsum,
                                                    float* __restrict__ dinv) {
    __shared__ int s[256];
    int tid = threadIdx.x;
    int i = blockIdx.x * 256 + tid;
    int v = (i < N_NODES) ? cnt[i] : 0;
    if (i < N_NODES) dinv[i] = rsqrtf(1.0f + (float)v);
    s[tid] = v;
    __syncthreads();
    #pragma unroll
    for (int off = 128; off > 0; off >>= 1) {
        if (tid < off) s[tid] += s[tid + off];
        __syncthreads();
    }
    if (tid == 0) bsum[blockIdx.x] = s[0];
}

// per-block scan + redundant in-block scan of the <=256 block sums (scan_bsums folded in)
__global__ __launch_bounds__(256) void block_scan(const int* __restrict__ cnt,
                                                  const int* __restrict__ bsum,
                                                  int* __restrict__ rowptr,
                                                  int* __restrict__ cursor) {
    __shared__ int s[256], sb[256];
    int tid = threadIdx.x;
    int i = blockIdx.x * 256 + tid;
    // scan the block sums (every block does this redundantly; 196 elems, cheap)
    int bv = (tid < NBLK) ? bsum[tid] : 0;
    sb[tid] = bv;
    __syncthreads();
    #pragma unroll
    for (int off = 1; off < 256; off <<= 1) {
        int t = (tid >= off) ? sb[tid - off] : 0;
        __syncthreads();
        sb[tid] += t;
        __syncthreads();
    }
    const int base = (blockIdx.x == 0) ? 0 : sb[blockIdx.x - 1];   // exclusive prefix
    // per-element scan within the block
    int v = (i < N_NODES) ? cnt[i] : 0;
    s[tid] = v;
    __syncthreads();
    #pragma unroll
    for (int off = 1; off < 256; off <<= 1) {
        int t = (tid >= off) ? s[tid - off] : 0;
        __syncthreads();
        s[tid] += t;
        __syncthreads();
    }
    if (i < N_NODES) {
        int val = base + s[tid] - v;   // exclusive: start of row i
        rowptr[i] = val;
        cursor[i] = val;
        if (i == N_NODES - 1) rowptr[N_NODES] = base + s[tid];
    }
}

__global__ void fill_csr(const int* __restrict__ src, const int* __restrict__ dst,
                         int* __restrict__ cursor, int* __restrict__ col) {
    int e = blockIdx.x * blockDim.x + threadIdx.x;
    if (e < N_EDGES) {
        int d = dst[e];
        int p = atomicAdd(&cursor[d], 1);
        col[p] = src[e];
    }
}

// both W1 and W2 in one launch
__global__ void transpose_w2(const float* __restrict__ W1f, const float* __restrict__ W2f,
                             unsigned short* __restrict__ WT1, unsigned short* __restrict__ WT2) {
    int k = blockIdx.x & 255;
    const float* W = (blockIdx.x >> 8) ? W2f : W1f;
    unsigned short* WT = (blockIdx.x >> 8) ? WT2 : WT1;
    int n = threadIdx.x;
    WT[n * CH + k] = f2b(W[k * CH + n]);
}

// ---------------- MFMA GEMMs (round-9 verified)
#define BM 128
#define BN 128
#define BK 64
#define SWZ(row, kb) (((row) * 128 + (kb) * 16) ^ (((row) & 7) << 4))

// layer 2: A bf16 (ws buffer, padded) -> both tiles via global_load_lds (pre-swizzled source)
__global__ __launch_bounds__(256) void gemm_bf16(const unsigned short* __restrict__ A,
                                                 const unsigned short* __restrict__ BT,
                                                 const float* __restrict__ dinv,
                                                 unsigned short* __restrict__ out) {
    __shared__ unsigned short As[BM * BK];
    __shared__ unsigned short Bs[BN * BK];
    const int row0 = blockIdx.x * BM;
    const int col0 = blockIdx.y * BN;
    const int tid = threadIdx.x;
    const int w = tid >> 6, l = tid & 63;
    const int wr = w >> 1, wc = w & 1;
    const int lr = l & 15, lg = l >> 4;
    const int sr = l >> 3, kbp = l & 7;

    f32x4 acc[4][4] = {};

    for (int k0 = 0; k0 < CH; k0 += BK) {
        #pragma unroll
        for (int it = 0; it < 4; it++) {
            const int R = (w * 4 + it) * 8;
            const int r = R + sr;
            const int kb = kbp ^ (r & 7);
            gload16(&A[(size_t)(row0 + r) * CH + k0 + kb * 8], (char*)As + R * 128);
            gload16(&BT[(size_t)(col0 + r) * CH + k0 + kb * 8], (char*)Bs + R * 128);
        }
        __syncthreads();
        #pragma unroll
        for (int ks = 0; ks < 2; ks++) {
            bf16x8 af[4], bfr[4];
            #pragma unroll
            for (int fm = 0; fm < 4; fm++) {
                int r = wr * 64 + fm * 16 + lr;
                af[fm] = *(const bf16x8*)((const char*)As + SWZ(r, ks * 4 + lg));
            }
            #pragma unroll
            for (int fn = 0; fn < 4; fn++) {
                int r = wc * 64 + fn * 16 + lr;
                bfr[fn] = *(const bf16x8*)((const char*)Bs + SWZ(r, ks * 4 + lg));
            }
            #pragma unroll
            for (int fm = 0; fm < 4; fm++)
                #pragma unroll
                for (int fn = 0; fn < 4; fn++)
                    acc[fm][fn] = __builtin_amdgcn_mfma_f32_16x16x32_bf16(af[fm], bfr[fn], acc[fm][fn], 0, 0, 0);
        }
        __syncthreads();
    }
    #pragma unroll
    for (int fm = 0; fm < 4; fm++) {
        #pragma unroll
        for (int r = 0; r < 4; r++) {
            int grow = row0 + wr * 64 + fm * 16 + lg * 4 + r;
            if (grow < N_NODES) {
                float s = dinv[grow];
                #pragma unroll
                for (int fn = 0; fn < 4; fn++) {
                    int gcol = col0 + wc * 64 + fn * 16 + lr;
                    out[(size_t)grow * CH + gcol] = f2b(acc[fm][fn][r] * s);
                }
            }
        }
    }
}

// layer 1: A f32 (guarded reg staging + cvt); B via global_load_lds
__global__ __launch_bounds__(256) void gemm_f32a(const float* __restrict__ Af,
                                                 const unsigned short* __restrict__ BT,
                                                 const float* __restrict__ dinv,
                                                 unsigned short* __restrict__ out) {
    __shared__ unsigned short As[BM * BK];
    __shared__ unsigned short Bs[BN * BK];
    const int row0 = blockIdx.x * BM;
    const int col0 = blockIdx.y * BN;
    const int tid = threadIdx.x;
    const int w = tid >> 6, l = tid & 63;
    const int wr = w >> 1, wc = w & 1;
    const int lr = l & 15, lg = l >> 4;
    const int sr = l >> 3, kbp = l & 7;

    f32x4 acc[4][4] = {};

    for (int k0 = 0; k0 < CH; k0 += BK) {
        #pragma unroll
        for (int it = 0; it < 4; it++) {
            const int R = (w * 4 + it) * 8;
            const int r = R + sr;
            const int kb = kbp ^ (r & 7);
            gload16(&BT[(size_t)(col0 + r) * CH + k0 + kb * 8], (char*)Bs + R * 128);
        }
        #pragma unroll
        for (int it = 0; it < 4; it++) {
            int cidx = it * 256 + tid;
            int r = cidx >> 3, kb = cidx & 7;
            int grow = row0 + r;
            uint4 ua = make_uint4(0u, 0u, 0u, 0u);
            if (grow < N_NODES) {
                const float* ap = &Af[(size_t)grow * CH + k0 + kb * 8];
                float4 v0 = *(const float4*)ap;
                float4 v1 = *(const float4*)(ap + 4);
                ua = make_uint4(pack2(v0.x, v0.y), pack2(v0.z, v0.w),
                                pack2(v1.x, v1.y), pack2(v1.z, v1.w));
            }
            *(uint4*)((char*)As + SWZ(r, kb)) = ua;
        }
        __syncthreads();
        #pragma unroll
        for (int ks = 0; ks < 2; ks++) {
            bf16x8 af[4], bfr[4];
            #pragma unroll
            for (int fm = 0; fm < 4; fm++) {
                int r = wr * 64 + fm * 16 + lr;
                af[fm] = *(const bf16x8*)((const char*)As + SWZ(r, ks * 4 + lg));
            }
            #pragma unroll
            for (int fn = 0; fn < 4; fn++) {
                int r = wc * 64 + fn * 16 + lr;
                bfr[fn] = *(const bf16x8*)((const char*)Bs + SWZ(r, ks * 4 + lg));
            }
            #pragma unroll
            for (int fm = 0; fm < 4; fm++)
                #pragma unroll
                for (int fn = 0; fn < 4; fn++)
                    acc[fm][fn] = __builtin_amdgcn_mfma_f32_16x16x32_bf16(af[fm], bfr[fn], acc[fm][fn], 0, 0, 0);
        }
        __syncthreads();
    }
    #pragma unroll
    for (int fm = 0; fm < 4; fm++) {
        #pragma unroll
        for (int r = 0; r < 4; r++) {
            int grow = row0 + wr * 64 + fm * 16 + lg * 4 + r;
            if (grow < N_NODES) {
                float s = dinv[grow];
                #pragma unroll
                for (int fn = 0; fn < 4; fn++) {
                    int gcol = col0 + wc * 64 + fn * 16 + lr;
                    out[(size_t)grow * CH + gcol] = f2b(acc[fm][fn][r] * s);
                }
            }
        }
    }
}

// ---------------- aggregation + LN + LeakyReLU, one WAVE per node, uint4 loads:
// 32 lanes x 16B = one 512B row -> each wave memory instruction covers TWO edges
// (es = lane>>5 selects edge, c = lane&31 selects 16B chunk = 8 channels).
// Halves VMEM instruction + shfl count vs uint2 form; identical bytes & coalescing.
__global__ __launch_bounds__(256) void agg_ln_bf16(const unsigned short* __restrict__ h,
                                                   const int* __restrict__ rowptr,
                                                   const int* __restrict__ col,
                                                   const float* __restrict__ dinv,
                                                   const float* __restrict__ bias,
                                                   const float* __restrict__ lnw,
                                                   const float* __restrict__ lnb,
                                                   unsigned short* __restrict__ out) {
    const int w = threadIdx.x >> 6, lane = threadIdx.x & 63;
    const int d = blockIdx.x * 4 + w;
    if (d >= N_NODES) return;   // wave-uniform exit
    const int c = lane & 31, es = lane >> 5;
    const uint4* __restrict__ h4 = (const uint4*)h;   // 32 uint4 per node row

    f32x2 a01 = {0.f, 0.f}, a23 = {0.f, 0.f}, a45 = {0.f, 0.f}, a67 = {0.f, 0.f};
    if (es == 0) {                                     // self loop added once
        uint4 u = h4[(size_t)d * 32 + c];
        a01 = b2f2(u.x); a23 = b2f2(u.y); a45 = b2f2(u.z); a67 = b2f2(u.w);
    }

    const int e0 = rowptr[d], e1 = rowptr[d + 1];
    for (int base = e0; base < e1; base += 64) {
        int n = e1 - base; if (n > 64) n = 64;
        int cidx = (lane < n) ? col[base + lane] : 0;
        const int pairs = n >> 1;
        int j = 0;
        for (; j + 4 <= pairs; j += 4) {   // 8 edges in flight per iteration
            int s0 = __shfl(cidx, (j + 0) * 2 + es);
            int s1 = __shfl(cidx, (j + 1) * 2 + es);
            int s2 = __shfl(cidx, (j + 2) * 2 + es);
            int s3 = __shfl(cidx, (j + 3) * 2 + es);
            uint4 u0 = h4[(size_t)s0 * 32 + c];
            uint4 u1 = h4[(size_t)s1 * 32 + c];
            uint4 u2 = h4[(size_t)s2 * 32 + c];
            uint4 u3 = h4[(size_t)s3 * 32 + c];
            a01 += b2f2(u0.x) + b2f2(u1.x) + b2f2(u2.x) + b2f2(u3.x);
            a23 += b2f2(u0.y) + b2f2(u1.y) + b2f2(u2.y) + b2f2(u3.y);
            a45 += b2f2(u0.z) + b2f2(u1.z) + b2f2(u2.z) + b2f2(u3.z);
            a67 += b2f2(u0.w) + b2f2(u1.w) + b2f2(u2.w) + b2f2(u3.w);
        }
        for (; j < pairs; j++) {
            int s = __shfl(cidx, j * 2 + es);
            uint4 u = h4[(size_t)s * 32 + c];
            a01 += b2f2(u.x); a23 += b2f2(u.y); a45 += b2f2(u.z); a67 += b2f2(u.w);
        }
        if (n & 1) {                        // odd remainder: edge n-1, es==0 group only
            int s = __shfl(cidx, n - 1);
            if (es == 0) {
                uint4 u = h4[(size_t)s * 32 + c];
                a01 += b2f2(u.x); a23 += b2f2(u.y); a45 += b2f2(u.z); a67 += b2f2(u.w);
            }
        }
    }
    // fold the two edge-groups: lane i and i+32 hold partials of the same 8 channels
    a01.x += __shfl_xor(a01.x, 32); a01.y += __shfl_xor(a01.y, 32);
    a23.x += __shfl_xor(a23.x, 32); a23.y += __shfl_xor(a23.y, 32);
    a45.x += __shfl_xor(a45.x, 32); a45.y += __shfl_xor(a45.y, 32);
    a67.x += __shfl_xor(a67.x, 32); a67.y += __shfl_xor(a67.y, 32);

    const float di = dinv[d];
    float4 bb0 = ((const float4*)bias)[c * 2];
    float4 bb1 = ((const float4*)bias)[c * 2 + 1];
    float x0 = a01.x * di + bb0.x, x1 = a01.y * di + bb0.y;
    float x2 = a23.x * di + bb0.z, x3 = a23.y * di + bb0.w;
    float x4 = a45.x * di + bb1.x, x5 = a45.y * di + bb1.y;
    float x6 = a67.x * di + bb1.z, x7 = a67.y * di + bb1.w;

    float s1 = x0 + x1 + x2 + x3 + x4 + x5 + x6 + x7;
    float s2 = x0 * x0 + x1 * x1 + x2 * x2 + x3 * x3 + x4 * x4 + x5 * x5 + x6 * x6 + x7 * x7;
    #pragma unroll
    for (int off = 1; off < 32; off <<= 1) {   // halves identical, 32-reduce suffices
        s1 += __shfl_xor(s1, off);
        s2 += __shfl_xor(s2, off);
    }
    const float mu = s1 * (1.0f / CH);
    const float rstd = rsqrtf(s2 * (1.0f / CH) - mu * mu + LN_EPS);
    float4 w0 = ((const float4*)lnw)[c * 2];
    float4 w1 = ((const float4*)lnw)[c * 2 + 1];
    float4 b0 = ((const float4*)lnb)[c * 2];
    float4 b1 = ((const float4*)lnb)[c * 2 + 1];
    float y0 = (x0 - mu) * rstd * w0.x + b0.x;
    float y1 = (x1 - mu) * rstd * w0.y + b0.y;
    float y2 = (x2 - mu) * rstd * w0.z + b0.z;
    float y3 = (x3 - mu) * rstd * w0.w + b0.w;
    float y4 = (x4 - mu) * rstd * w1.x + b1.x;
    float y5 = (x5 - mu) * rstd * w1.y + b1.y;
    float y6 = (x6 - mu) * rstd * w1.z + b1.z;
    float y7 = (x7 - mu) * rstd * w1.w + b1.w;
    y0 = fmaxf(y0, LEAKY * y0); y1 = fmaxf(y1, LEAKY * y1);
    y2 = fmaxf(y2, LEAKY * y2); y3 = fmaxf(y3, LEAKY * y3);
    y4 = fmaxf(y4, LEAKY * y4); y5 = fmaxf(y5, LEAKY * y5);
    y6 = fmaxf(y6, LEAKY * y6); y7 = fmaxf(y7, LEAKY * y7);
    if (es == 0) {
        uint4 o = make_uint4(pack2(y0, y1), pack2(y2, y3), pack2(y4, y5), pack2(y6, y7));
        ((uint4*)out)[(size_t)d * 32 + c] = o;
    }
}

// 4 waves per graph, node range split across waves, LDS cross-wave reduce
__global__ __launch_bounds__(256) void pool_mean_bf16(const unsigned short* __restrict__ feat,
                                                      const int* __restrict__ batch,
                                                      float* __restrict__ out) {
    const int g = blockIdx.x;
    const int w = threadIdx.x >> 6, lane = threadIdx.x & 63;
    int lo = 0, hi = N_NODES;
    while (lo < hi) { int mid = (lo + hi) >> 1; if (batch[mid] < g) lo = mid + 1; else hi = mid; }
    const int start = lo;
    hi = N_NODES;
    while (lo < hi) { int mid = (lo + hi) >> 1; if (batch[mid] < g + 1) lo = mid + 1; else hi = mid; }
    const int end = lo;

    float a0 = 0.f, a1 = 0.f, a2 = 0.f, a3 = 0.f;
    for (int n = start + w; n < end; n += 4) {
        ushort4 u = *(const ushort4*)&feat[(size_t)n * CH + lane * 4];
        a0 += b2f(u.x); a1 += b2f(u.y); a2 += b2f(u.z); a3 += b2f(u.w);
    }
    __shared__ float4 red[4][64];
    red[w][lane] = make_float4(a0, a1, a2, a3);
    __syncthreads();
    if (w == 0) {
        float4 t0 = red[0][lane], t1 = red[1][lane], t2 = red[2][lane], t3 = red[3][lane];
        const float inv = (end > start) ? 1.0f / (float)(end - start) : 0.0f;
        float4 o = make_float4((t0.x + t1.x + t2.x + t3.x) * inv,
                               (t0.y + t1.y + t2.y + t3.y) * inv,
                               (t0.z + t1.z + t2.z + t3.z) * inv,
                               (t0.w + t1.w + t2.w + t3.w) * inv);
        *(float4*)&out[(size_t)g * CH + lane * 4] = o;
    }
}

static inline size_t align256(size_t x) { return (x + 255) & ~(size_t)255; }

extern "C" void kernel_launch(void* const* d_in, const int* in_sizes, int n_in,
                              void* d_out, int out_size, void* d_ws, size_t ws_size,
                              hipStream_t stream) {
    const float* x    = (const float*)d_in[0];
    const int*   edge = (const int*)d_in[1];
    const int*   batch= (const int*)d_in[2];
    const float* W1   = (const float*)d_in[3];
    const float* b1   = (const float*)d_in[4];
    const float* ln1w = (const float*)d_in[5];
    const float* ln1b = (const float*)d_in[6];
    const float* W2   = (const float*)d_in[7];
    const float* b2   = (const float*)d_in[8];
    const float* ln2w = (const float*)d_in[9];
    const float* ln2b = (const float*)d_in[10];

    const int* src = edge;
    const int* dst = edge + N_EDGES;

    char* p = (char*)d_ws;
    int* cnt    = (int*)p;  p += align256(N_NODES * 4);
    int* cursor = (int*)p;  p += align256(N_NODES * 4);
    int* rowptr = (int*)p;  p += align256((N_NODES + 1) * 4);
    int* bsum   = (int*)p;  p += align256(NBLK * 4);
    float* dinv = (float*)p; p += align256(N_NODES * 4);
    int* col    = (int*)p;  p += align256(N_EDGES * 4);
    unsigned short* wt1 = (unsigned short*)p; p += align256(CH * CH * 2);
    unsigned short* wt2 = (unsigned short*)p; p += align256(CH * CH * 2);
    unsigned short* bufA = (unsigned short*)p; p += align256((size_t)N_NODES * CH * 2);  // h
    unsigned short* bufB = (unsigned short*)p; p += align256((size_t)N_NODES * CH * 2);  // y
    p += 32768;  // OOB-read pad for gemm_bf16's unguarded global_load_lds tail rows

    zero_ints<<<(N_NODES + 255) / 256, 256, 0, stream>>>(cnt, N_NODES);
    count_deg<<<(N_EDGES + 255) / 256, 256, 0, stream>>>(dst, cnt);
    block_reduce<<<NBLK, 256, 0, stream>>>(cnt, bsum, dinv);
    block_scan<<<NBLK, 256, 0, stream>>>(cnt, bsum, rowptr, cursor);
    fill_csr<<<(N_EDGES + 255) / 256, 256, 0, stream>>>(src, dst, cursor, col);
    transpose_w2<<<2 * CH, 256, 0, stream>>>(W1, W2, wt1, wt2);

    dim3 ggrid((N_NODES + BM - 1) / BM, CH / BN);
    gemm_f32a<<<ggrid, 256, 0, stream>>>(x, wt1, dinv, bufA);
    agg_ln_bf16<<<(N_NODES + 3) / 4, 256, 0, stream>>>(bufA, rowptr, col, dinv, b1, ln1w, ln1b, bufB);
    gemm_bf16<<<ggrid, 256, 0, stream>>>(bufB, wt2, dinv, bufA);
    agg_ln_bf16<<<(N_NODES + 3) / 4, 256, 0, stream>>>(bufA, rowptr, col, dinv, b2, ln2w, ln2b, bufB);
    pool_mean_bf16<<<NUM_GRAPHS, 256, 0, stream>>>(bufB, batch, (float*)d_out);
}